// Round 1
// baseline (856.775 us; speedup 1.0000x reference)
//
#include <hip/hip_runtime.h>

#define S_TOT 32768
#define C_IN 192
#define NB 2
#define NH 8
#define DH 64
#define ATT_SCALE 0.125f

// workspace layout (float offsets)
#define G_OFF   0
#define G_SZ    (NB * C_IN * C_IN)        // 73728
#define ATT_OFF (G_OFF + G_SZ)
#define ATT_SZ  (NB * NH * DH * DH)       // 65536
#define M_OFF   (ATT_OFF + ATT_SZ)
#define M_SZ    (NB * 512 * C_IN)         // 196608
#define W_OFF   (M_OFF + M_SZ)
#define W_SZ    (NB * C_IN * C_IN)        // 73728

#define KCH 32
#define KLEN (S_TOT / KCH)                // 1024

// ---------------- Gram: G[b] = X_b * X_b^T, X_b = [192, 32768] ----------------
// grid (3, 3, NB*KCH), block 256. 64x64 tile, K-chunk 1024, atomicAdd partials.
__global__ __launch_bounds__(256) void gram_kernel(const float* __restrict__ x,
                                                   float* __restrict__ G) {
    int b   = blockIdx.z >> 5;
    int kc  = blockIdx.z & 31;
    int ci0 = blockIdx.x * 64;
    int cj0 = blockIdx.y * 64;
    int k0  = kc * KLEN;

    __shared__ float As[16][68];
    __shared__ float Bs[16][68];

    int tid = threadIdx.x;
    int tx = tid & 15, ty = tid >> 4;
    int lrow = tid >> 2;          // 0..63
    int lk   = (tid & 3) * 4;     // 0,4,8,12

    const float* xb = x + (size_t)b * C_IN * S_TOT;
    const float* pa = xb + (size_t)(ci0 + lrow) * S_TOT + k0 + lk;
    const float* pb = xb + (size_t)(cj0 + lrow) * S_TOT + k0 + lk;

    float acc[4][4] = {};

    for (int ks = 0; ks < KLEN; ks += 16) {
        float4 av = *(const float4*)(pa + ks);
        float4 bv = *(const float4*)(pb + ks);
        __syncthreads();
        As[lk + 0][lrow] = av.x; As[lk + 1][lrow] = av.y;
        As[lk + 2][lrow] = av.z; As[lk + 3][lrow] = av.w;
        Bs[lk + 0][lrow] = bv.x; Bs[lk + 1][lrow] = bv.y;
        Bs[lk + 2][lrow] = bv.z; Bs[lk + 3][lrow] = bv.w;
        __syncthreads();
#pragma unroll
        for (int kk = 0; kk < 16; kk++) {
            float4 a = *(const float4*)&As[kk][ty * 4];
            float4 bb = *(const float4*)&Bs[kk][tx * 4];
            acc[0][0] += a.x * bb.x; acc[0][1] += a.x * bb.y; acc[0][2] += a.x * bb.z; acc[0][3] += a.x * bb.w;
            acc[1][0] += a.y * bb.x; acc[1][1] += a.y * bb.y; acc[1][2] += a.y * bb.z; acc[1][3] += a.y * bb.w;
            acc[2][0] += a.z * bb.x; acc[2][1] += a.z * bb.y; acc[2][2] += a.z * bb.z; acc[2][3] += a.z * bb.w;
            acc[3][0] += a.w * bb.x; acc[3][1] += a.w * bb.y; acc[3][2] += a.w * bb.z; acc[3][3] += a.w * bb.w;
        }
    }

    float* Gb = G + b * C_IN * C_IN;
#pragma unroll
    for (int r = 0; r < 4; r++)
#pragma unroll
        for (int c = 0; c < 4; c++)
            atomicAdd(&Gb[(ci0 + ty * 4 + r) * C_IN + (cj0 + tx * 4 + c)], acc[r][c]);
}

// ---------------- attn: sim = wq_h G wk_h^T * SCALE -> softmax rows ----------------
// grid (NB, NH), block 256.
__global__ __launch_bounds__(256) void attn_kernel(const float* __restrict__ wq,
                                                   const float* __restrict__ wk,
                                                   const float* __restrict__ G,
                                                   float* __restrict__ attn) {
    int b = blockIdx.x, h = blockIdx.y;
    __shared__ float Tl[64][193];   // pad 193: phase-2 reads conflict-free
    const float* Gb = G + b * C_IN * C_IN;
    int tid = threadIdx.x;

    // T[i][cp] = sum_c wq[h*64+i][c] * G[c][cp]
    for (int idx = tid; idx < 64 * C_IN; idx += 256) {
        int i = idx / C_IN, cp = idx - i * C_IN;
        const float* wqr = wq + (h * 64 + i) * C_IN;
        float s0 = 0, s1 = 0, s2 = 0, s3 = 0;
        for (int c = 0; c < C_IN; c += 4) {
            s0 += wqr[c + 0] * Gb[(c + 0) * C_IN + cp];
            s1 += wqr[c + 1] * Gb[(c + 1) * C_IN + cp];
            s2 += wqr[c + 2] * Gb[(c + 2) * C_IN + cp];
            s3 += wqr[c + 3] * Gb[(c + 3) * C_IN + cp];
        }
        Tl[i][cp] = (s0 + s1) + (s2 + s3);
    }
    __syncthreads();

    // each thread: row i = tid>>2, j-range (tid&3)*16 .. +15
    int i = tid >> 2;
    int jg = tid & 3;
    float sim[16];
#pragma unroll
    for (int jj = 0; jj < 16; jj++) {
        int j = jg * 16 + jj;
        const float* wkr = wk + (h * 64 + j) * C_IN;
        float s0 = 0, s1 = 0, s2 = 0, s3 = 0;
        for (int c = 0; c < C_IN; c += 4) {
            s0 += Tl[i][c + 0] * wkr[c + 0];
            s1 += Tl[i][c + 1] * wkr[c + 1];
            s2 += Tl[i][c + 2] * wkr[c + 2];
            s3 += Tl[i][c + 3] * wkr[c + 3];
        }
        sim[jj] = ((s0 + s1) + (s2 + s3)) * ATT_SCALE;
    }

    // softmax over 64 j's held by 4 adjacent lanes
    float mx = sim[0];
#pragma unroll
    for (int jj = 1; jj < 16; jj++) mx = fmaxf(mx, sim[jj]);
    mx = fmaxf(mx, __shfl_xor(mx, 1));
    mx = fmaxf(mx, __shfl_xor(mx, 2));
    float e[16], sum = 0.f;
#pragma unroll
    for (int jj = 0; jj < 16; jj++) { e[jj] = __expf(sim[jj] - mx); sum += e[jj]; }
    sum += __shfl_xor(sum, 1);
    sum += __shfl_xor(sum, 2);
    float inv = 1.0f / sum;

    float* ab = attn + ((b * NH + h) * 64 * 64) + i * 64 + jg * 16;
#pragma unroll
    for (int q = 0; q < 4; q++) {
        float4 v = { e[q * 4 + 0] * inv, e[q * 4 + 1] * inv, e[q * 4 + 2] * inv, e[q * 4 + 3] * inv };
        *(float4*)(ab + q * 4) = v;
    }
}

// ---------------- M[b][h*64+i][c] = sum_j attn[b,h,i,j] * wv[h*64+j][c] ----------------
// grid (NB, NH), block 256.
__global__ __launch_bounds__(256) void m_kernel(const float* __restrict__ attn,
                                                const float* __restrict__ wv,
                                                float* __restrict__ M) {
    int b = blockIdx.x, h = blockIdx.y;
    __shared__ float A[64][64];
    const float* ab = attn + (b * NH + h) * 4096;
    int tid = threadIdx.x;
    for (int idx = tid; idx < 4096; idx += 256) A[idx >> 6][idx & 63] = ab[idx];
    __syncthreads();
    float* Mb = M + b * 512 * C_IN + h * 64 * C_IN;
    for (int idx = tid; idx < 64 * C_IN; idx += 256) {
        int i = idx / C_IN, c = idx - i * C_IN;
        float s0 = 0, s1 = 0, s2 = 0, s3 = 0;
        const float* wvb = wv + (h * 64) * C_IN + c;
#pragma unroll 4
        for (int j = 0; j < 64; j += 4) {
            s0 += A[i][j + 0] * wvb[(j + 0) * C_IN];
            s1 += A[i][j + 1] * wvb[(j + 1) * C_IN];
            s2 += A[i][j + 2] * wvb[(j + 2) * C_IN];
            s3 += A[i][j + 3] * wvb[(j + 3) * C_IN];
        }
        Mb[i * C_IN + c] = (s0 + s1) + (s2 + s3);
    }
}

// ---------------- W[b][o][c] = sum_c5 wo[o][c5] * M[b][c5][c] ----------------
// grid (NB, 12), block 256: each block 16 rows of o.
__global__ __launch_bounds__(256) void w_kernel(const float* __restrict__ wo,
                                                const float* __restrict__ M,
                                                float* __restrict__ W) {
    int b = blockIdx.x;
    int o0 = blockIdx.y * 16;
    const float* Mb = M + b * 512 * C_IN;
    float* Wb = W + b * C_IN * C_IN;
    int tid = threadIdx.x;
    for (int idx = tid; idx < 16 * C_IN; idx += 256) {
        int ol = idx / C_IN, c = idx - ol * C_IN;
        const float* wor = wo + (o0 + ol) * 512;
        float s0 = 0, s1 = 0, s2 = 0, s3 = 0;
        for (int c5 = 0; c5 < 512; c5 += 4) {
            s0 += wor[c5 + 0] * Mb[(c5 + 0) * C_IN + c];
            s1 += wor[c5 + 1] * Mb[(c5 + 1) * C_IN + c];
            s2 += wor[c5 + 2] * Mb[(c5 + 2) * C_IN + c];
            s3 += wor[c5 + 3] * Mb[(c5 + 3) * C_IN + c];
        }
        Wb[(o0 + ol) * C_IN + c] = (s0 + s1) + (s2 + s3);
    }
}

// ---------------- out[b][o][s] = sum_c W[b][o][c] * x[b][c][s] + bo[o] ----------------
// grid (3, 256, NB), block 256. M=192, N=32768, K=192; tile 64x128, micro 4x8.
__global__ __launch_bounds__(256) void final_kernel(const float* __restrict__ x,
                                                    const float* __restrict__ Wm,
                                                    const float* __restrict__ bo,
                                                    float* __restrict__ out) {
    int m0 = blockIdx.x * 64;
    int n0 = blockIdx.y * 128;
    int b  = blockIdx.z;

    __shared__ float As[16][68];
    __shared__ float Xs[16][132];

    int tid = threadIdx.x;
    int tx = tid & 15, ty = tid >> 4;
    int lrow = tid >> 2, lk = (tid & 3) * 4;
    int c0 = tid >> 5, s0 = (tid & 31) * 4;          // B-tile load slot 0 (c 0..7)
    int c1 = c0 + 8;                                  // slot 1 (c 8..15)

    const float* Wb = Wm + b * C_IN * C_IN;
    const float* xb = x + (size_t)b * C_IN * S_TOT;

    float acc[4][8] = {};

    for (int k0 = 0; k0 < C_IN; k0 += 16) {
        float4 av  = *(const float4*)(Wb + (m0 + lrow) * C_IN + k0 + lk);
        float4 xv0 = *(const float4*)(xb + (size_t)(k0 + c0) * S_TOT + n0 + s0);
        float4 xv1 = *(const float4*)(xb + (size_t)(k0 + c1) * S_TOT + n0 + s0);
        __syncthreads();
        As[lk + 0][lrow] = av.x; As[lk + 1][lrow] = av.y;
        As[lk + 2][lrow] = av.z; As[lk + 3][lrow] = av.w;
        *(float4*)&Xs[c0][s0] = xv0;
        *(float4*)&Xs[c1][s0] = xv1;
        __syncthreads();
#pragma unroll
        for (int kk = 0; kk < 16; kk++) {
            float4 a  = *(const float4*)&As[kk][ty * 4];
            float4 b0 = *(const float4*)&Xs[kk][tx * 8];
            float4 b1 = *(const float4*)&Xs[kk][tx * 8 + 4];
            acc[0][0] += a.x * b0.x; acc[0][1] += a.x * b0.y; acc[0][2] += a.x * b0.z; acc[0][3] += a.x * b0.w;
            acc[0][4] += a.x * b1.x; acc[0][5] += a.x * b1.y; acc[0][6] += a.x * b1.z; acc[0][7] += a.x * b1.w;
            acc[1][0] += a.y * b0.x; acc[1][1] += a.y * b0.y; acc[1][2] += a.y * b0.z; acc[1][3] += a.y * b0.w;
            acc[1][4] += a.y * b1.x; acc[1][5] += a.y * b1.y; acc[1][6] += a.y * b1.z; acc[1][7] += a.y * b1.w;
            acc[2][0] += a.z * b0.x; acc[2][1] += a.z * b0.y; acc[2][2] += a.z * b0.z; acc[2][3] += a.z * b0.w;
            acc[2][4] += a.z * b1.x; acc[2][5] += a.z * b1.y; acc[2][6] += a.z * b1.z; acc[2][7] += a.z * b1.w;
            acc[3][0] += a.w * b0.x; acc[3][1] += a.w * b0.y; acc[3][2] += a.w * b0.z; acc[3][3] += a.w * b0.w;
            acc[3][4] += a.w * b1.x; acc[3][5] += a.w * b1.y; acc[3][6] += a.w * b1.z; acc[3][7] += a.w * b1.w;
        }
    }

#pragma unroll
    for (int r = 0; r < 4; r++) {
        int m = m0 + ty * 4 + r;
        float bias = bo[m];
        float* op = out + ((size_t)b * C_IN + m) * S_TOT + n0 + tx * 8;
        float4 v0 = { acc[r][0] + bias, acc[r][1] + bias, acc[r][2] + bias, acc[r][3] + bias };
        float4 v1 = { acc[r][4] + bias, acc[r][5] + bias, acc[r][6] + bias, acc[r][7] + bias };
        *(float4*)(op + 0) = v0;
        *(float4*)(op + 4) = v1;
    }
}

extern "C" void kernel_launch(void* const* d_in, const int* in_sizes, int n_in,
                              void* d_out, int out_size, void* d_ws, size_t ws_size,
                              hipStream_t stream) {
    const float* x  = (const float*)d_in[0];
    const float* wq = (const float*)d_in[1];
    const float* wk = (const float*)d_in[2];
    const float* wv = (const float*)d_in[3];
    const float* wo = (const float*)d_in[4];
    const float* bo = (const float*)d_in[5];
    float* out = (float*)d_out;
    float* ws  = (float*)d_ws;

    float* gG   = ws + G_OFF;
    float* gAtt = ws + ATT_OFF;
    float* gM   = ws + M_OFF;
    float* gW   = ws + W_OFF;

    hipMemsetAsync(gG, 0, G_SZ * sizeof(float), stream);
    gram_kernel<<<dim3(3, 3, NB * KCH), 256, 0, stream>>>(x, gG);
    attn_kernel<<<dim3(NB, NH), 256, 0, stream>>>(wq, wk, gG, gAtt);
    m_kernel<<<dim3(NB, NH), 256, 0, stream>>>(gAtt, wv, gM);
    w_kernel<<<dim3(NB, 12), 256, 0, stream>>>(wo, gM, gW);
    final_kernel<<<dim3(3, 256, NB), 256, 0, stream>>>(x, gW, bo, out);
}

// Round 2
// 334.601 us; speedup vs baseline: 2.5606x; 2.5606x over previous
//
#include <hip/hip_runtime.h>

#define S_TOT 32768
#define C_IN 192
#define NB 2
#define NH 8
#define DH 64
#define ATT_SCALE 0.125f

// workspace layout (float offsets)
#define G_OFF   0
#define G_SZ    (NB * C_IN * C_IN)        // 73728
#define T_OFF   (G_OFF + G_SZ)
#define T_SZ    (NB * 512 * C_IN)         // 196608
#define M_OFF   (T_OFF + T_SZ)
#define M_SZ    (NB * 512 * C_IN)         // 196608
#define W_OFF   (M_OFF + M_SZ)
#define W_SZ    (NB * C_IN * C_IN)        // 73728

#define KCH 32
#define KLEN (S_TOT / KCH)                // 1024

// ---------------- Gram: G[b] = X_b * X_b^T, X_b = [192, 32768] ----------------
// grid (3, 3, NB*KCH), block 256. 64x64 tile, K-chunk 1024, atomicAdd partials.
__global__ __launch_bounds__(256) void gram_kernel(const float* __restrict__ x,
                                                   float* __restrict__ G) {
    int b   = blockIdx.z >> 5;
    int kc  = blockIdx.z & 31;
    int ci0 = blockIdx.x * 64;
    int cj0 = blockIdx.y * 64;
    int k0  = kc * KLEN;

    __shared__ float As[16][68];
    __shared__ float Bs[16][68];

    int tid = threadIdx.x;
    int tx = tid & 15, ty = tid >> 4;
    int lrow = tid >> 2;          // 0..63
    int lk   = (tid & 3) * 4;     // 0,4,8,12

    const float* xb = x + (size_t)b * C_IN * S_TOT;
    const float* pa = xb + (size_t)(ci0 + lrow) * S_TOT + k0 + lk;
    const float* pb = xb + (size_t)(cj0 + lrow) * S_TOT + k0 + lk;

    float acc[4][4] = {};

    for (int ks = 0; ks < KLEN; ks += 16) {
        float4 av = *(const float4*)(pa + ks);
        float4 bv = *(const float4*)(pb + ks);
        __syncthreads();
        As[lk + 0][lrow] = av.x; As[lk + 1][lrow] = av.y;
        As[lk + 2][lrow] = av.z; As[lk + 3][lrow] = av.w;
        Bs[lk + 0][lrow] = bv.x; Bs[lk + 1][lrow] = bv.y;
        Bs[lk + 2][lrow] = bv.z; Bs[lk + 3][lrow] = bv.w;
        __syncthreads();
#pragma unroll
        for (int kk = 0; kk < 16; kk++) {
            float4 a = *(const float4*)&As[kk][ty * 4];
            float4 bb = *(const float4*)&Bs[kk][tx * 4];
            acc[0][0] += a.x * bb.x; acc[0][1] += a.x * bb.y; acc[0][2] += a.x * bb.z; acc[0][3] += a.x * bb.w;
            acc[1][0] += a.y * bb.x; acc[1][1] += a.y * bb.y; acc[1][2] += a.y * bb.z; acc[1][3] += a.y * bb.w;
            acc[2][0] += a.z * bb.x; acc[2][1] += a.z * bb.y; acc[2][2] += a.z * bb.z; acc[2][3] += a.z * bb.w;
            acc[3][0] += a.w * bb.x; acc[3][1] += a.w * bb.y; acc[3][2] += a.w * bb.z; acc[3][3] += a.w * bb.w;
        }
    }

    float* Gb = G + b * C_IN * C_IN;
#pragma unroll
    for (int r = 0; r < 4; r++)
#pragma unroll
        for (int c = 0; c < 4; c++)
            atomicAdd(&Gb[(ci0 + ty * 4 + r) * C_IN + (cj0 + tx * 4 + c)], acc[r][c]);
}

// ---------------- generic 64x64-tile GEMM: C[b] = A[b] (MxK) * B[b] (KxN) ----------------
// row-major, lda=K, ldb=N, ldc=N. grid (M/64, N/64, NB), block 256, micro 4x4.
__global__ __launch_bounds__(256) void gemm64_kernel(const float* __restrict__ A,
                                                     const float* __restrict__ B,
                                                     float* __restrict__ C,
                                                     int K, int N,
                                                     long aStride, long bStride, long cStride) {
    int mi0 = blockIdx.x * 64;
    int nj0 = blockIdx.y * 64;
    int b   = blockIdx.z;

    __shared__ float As[16][68];
    __shared__ float Bs[16][68];

    int tid = threadIdx.x;
    int tx = tid & 15, ty = tid >> 4;
    int lrow = tid >> 2, lk = (tid & 3) * 4;     // A staging (transposed)
    int ldk = tid >> 4, ldn = (tid & 15) * 4;    // B staging (direct)

    const float* Ab = A + b * aStride;
    const float* Bb = B + b * bStride;

    float acc[4][4] = {};

    for (int k0 = 0; k0 < K; k0 += 16) {
        float4 av = *(const float4*)(Ab + (size_t)(mi0 + lrow) * K + k0 + lk);
        float4 bv = *(const float4*)(Bb + (size_t)(k0 + ldk) * N + nj0 + ldn);
        __syncthreads();
        As[lk + 0][lrow] = av.x; As[lk + 1][lrow] = av.y;
        As[lk + 2][lrow] = av.z; As[lk + 3][lrow] = av.w;
        *(float4*)&Bs[ldk][ldn] = bv;
        __syncthreads();
#pragma unroll
        for (int kk = 0; kk < 16; kk++) {
            float4 a = *(const float4*)&As[kk][ty * 4];
            float4 bb = *(const float4*)&Bs[kk][tx * 4];
            acc[0][0] += a.x * bb.x; acc[0][1] += a.x * bb.y; acc[0][2] += a.x * bb.z; acc[0][3] += a.x * bb.w;
            acc[1][0] += a.y * bb.x; acc[1][1] += a.y * bb.y; acc[1][2] += a.y * bb.z; acc[1][3] += a.y * bb.w;
            acc[2][0] += a.z * bb.x; acc[2][1] += a.z * bb.y; acc[2][2] += a.z * bb.z; acc[2][3] += a.z * bb.w;
            acc[3][0] += a.w * bb.x; acc[3][1] += a.w * bb.y; acc[3][2] += a.w * bb.z; acc[3][3] += a.w * bb.w;
        }
    }

    float* Cb = C + b * cStride;
#pragma unroll
    for (int r = 0; r < 4; r++) {
        float4 v = { acc[r][0], acc[r][1], acc[r][2], acc[r][3] };
        *(float4*)(Cb + (size_t)(mi0 + ty * 4 + r) * N + nj0 + tx * 4) = v;
    }
}

// ---------------- fused: sim = T_h wk_h^T * SCALE -> softmax -> M_h = attn * wv_h ----------------
// grid (NB, NH), block 256.
__global__ __launch_bounds__(256) void simsoftm_kernel(const float* __restrict__ T,
                                                       const float* __restrict__ wk,
                                                       const float* __restrict__ wv,
                                                       float* __restrict__ M) {
    int b = blockIdx.x, h = blockIdx.y;

    __shared__ float As[16][68];
    __shared__ float Bs[16][68];
    __shared__ float At[64][68];   // attn TRANSPOSED: At[j][i]

    int tid = threadIdx.x;
    int tx = tid & 15, ty = tid >> 4;
    int lrow = tid >> 2, lk = (tid & 3) * 4;
    int ldk = tid >> 4, ldn = (tid & 15) * 4;

    const float* Th  = T + (size_t)b * 512 * C_IN + (size_t)(h * 64) * C_IN;
    const float* wkh = wk + (size_t)(h * 64) * C_IN;
    const float* wvh = wv + (size_t)(h * 64) * C_IN;

    // ---- phase 1: sim(i,j) = sum_c T_h[i][c] * wk_h[j][c]  (both transposed-staged) ----
    float acc[4][4] = {};
    for (int k0 = 0; k0 < C_IN; k0 += 16) {
        float4 av = *(const float4*)(Th  + (size_t)lrow * C_IN + k0 + lk);
        float4 bv = *(const float4*)(wkh + (size_t)lrow * C_IN + k0 + lk);
        __syncthreads();
        As[lk + 0][lrow] = av.x; As[lk + 1][lrow] = av.y;
        As[lk + 2][lrow] = av.z; As[lk + 3][lrow] = av.w;
        Bs[lk + 0][lrow] = bv.x; Bs[lk + 1][lrow] = bv.y;
        Bs[lk + 2][lrow] = bv.z; Bs[lk + 3][lrow] = bv.w;
        __syncthreads();
#pragma unroll
        for (int kk = 0; kk < 16; kk++) {
            float4 a = *(const float4*)&As[kk][ty * 4];
            float4 bb = *(const float4*)&Bs[kk][tx * 4];
            acc[0][0] += a.x * bb.x; acc[0][1] += a.x * bb.y; acc[0][2] += a.x * bb.z; acc[0][3] += a.x * bb.w;
            acc[1][0] += a.y * bb.x; acc[1][1] += a.y * bb.y; acc[1][2] += a.y * bb.z; acc[1][3] += a.y * bb.w;
            acc[2][0] += a.z * bb.x; acc[2][1] += a.z * bb.y; acc[2][2] += a.z * bb.z; acc[2][3] += a.z * bb.w;
            acc[3][0] += a.w * bb.x; acc[3][1] += a.w * bb.y; acc[3][2] += a.w * bb.z; acc[3][3] += a.w * bb.w;
        }
    }

    // ---- softmax per row i = ty*4+r over the 16 lanes (tx) holding that row ----
#pragma unroll
    for (int r = 0; r < 4; r++) {
        float s0 = acc[r][0] * ATT_SCALE, s1 = acc[r][1] * ATT_SCALE;
        float s2 = acc[r][2] * ATT_SCALE, s3 = acc[r][3] * ATT_SCALE;
        float mx = fmaxf(fmaxf(s0, s1), fmaxf(s2, s3));
        mx = fmaxf(mx, __shfl_xor(mx, 1));
        mx = fmaxf(mx, __shfl_xor(mx, 2));
        mx = fmaxf(mx, __shfl_xor(mx, 4));
        mx = fmaxf(mx, __shfl_xor(mx, 8));
        float e0 = __expf(s0 - mx), e1 = __expf(s1 - mx);
        float e2 = __expf(s2 - mx), e3 = __expf(s3 - mx);
        float sum = (e0 + e1) + (e2 + e3);
        sum += __shfl_xor(sum, 1);
        sum += __shfl_xor(sum, 2);
        sum += __shfl_xor(sum, 4);
        sum += __shfl_xor(sum, 8);
        float inv = 1.0f / sum;
        At[tx * 4 + 0][ty * 4 + r] = e0 * inv;
        At[tx * 4 + 1][ty * 4 + r] = e1 * inv;
        At[tx * 4 + 2][ty * 4 + r] = e2 * inv;
        At[tx * 4 + 3][ty * 4 + r] = e3 * inv;
    }

    // ---- phase 2: M_h(i,c) = sum_j attn(i,j) * wv_h(j,c) ; At[j][i] is A-transposed ----
    float* Mb = M + (size_t)b * 512 * C_IN + (size_t)(h * 64) * C_IN;
    for (int nj = 0; nj < C_IN; nj += 64) {
        float acc2[4][4] = {};
        for (int j0 = 0; j0 < 64; j0 += 16) {
            float4 bv = *(const float4*)(wvh + (size_t)(j0 + ldk) * C_IN + nj + ldn);
            __syncthreads();
            *(float4*)&Bs[ldk][ldn] = bv;
            __syncthreads();
#pragma unroll
            for (int kk = 0; kk < 16; kk++) {
                float4 a = *(const float4*)&At[j0 + kk][ty * 4];
                float4 bb = *(const float4*)&Bs[kk][tx * 4];
                acc2[0][0] += a.x * bb.x; acc2[0][1] += a.x * bb.y; acc2[0][2] += a.x * bb.z; acc2[0][3] += a.x * bb.w;
                acc2[1][0] += a.y * bb.x; acc2[1][1] += a.y * bb.y; acc2[1][2] += a.y * bb.z; acc2[1][3] += a.y * bb.w;
                acc2[2][0] += a.z * bb.x; acc2[2][1] += a.z * bb.y; acc2[2][2] += a.z * bb.z; acc2[2][3] += a.z * bb.w;
                acc2[3][0] += a.w * bb.x; acc2[3][1] += a.w * bb.y; acc2[3][2] += a.w * bb.z; acc2[3][3] += a.w * bb.w;
            }
        }
#pragma unroll
        for (int r = 0; r < 4; r++) {
            float4 v = { acc2[r][0], acc2[r][1], acc2[r][2], acc2[r][3] };
            *(float4*)(Mb + (size_t)(ty * 4 + r) * C_IN + nj + tx * 4) = v;
        }
    }
}

// ---------------- out[b][o][s] = sum_c W[b][o][c] * x[b][c][s] + bo[o] ----------------
// grid (3, 256, NB), block 256. M=192, N=32768, K=192; tile 64x128, micro 4x8.
__global__ __launch_bounds__(256) void final_kernel(const float* __restrict__ x,
                                                    const float* __restrict__ Wm,
                                                    const float* __restrict__ bo,
                                                    float* __restrict__ out) {
    int m0 = blockIdx.x * 64;
    int n0 = blockIdx.y * 128;
    int b  = blockIdx.z;

    __shared__ float As[16][68];
    __shared__ float Xs[16][132];

    int tid = threadIdx.x;
    int tx = tid & 15, ty = tid >> 4;
    int lrow = tid >> 2, lk = (tid & 3) * 4;
    int c0 = tid >> 5, s0 = (tid & 31) * 4;          // B-tile load slot 0 (c 0..7)
    int c1 = c0 + 8;                                  // slot 1 (c 8..15)

    const float* Wb = Wm + b * C_IN * C_IN;
    const float* xb = x + (size_t)b * C_IN * S_TOT;

    float acc[4][8] = {};

    for (int k0 = 0; k0 < C_IN; k0 += 16) {
        float4 av  = *(const float4*)(Wb + (m0 + lrow) * C_IN + k0 + lk);
        float4 xv0 = *(const float4*)(xb + (size_t)(k0 + c0) * S_TOT + n0 + s0);
        float4 xv1 = *(const float4*)(xb + (size_t)(k0 + c1) * S_TOT + n0 + s0);
        __syncthreads();
        As[lk + 0][lrow] = av.x; As[lk + 1][lrow] = av.y;
        As[lk + 2][lrow] = av.z; As[lk + 3][lrow] = av.w;
        *(float4*)&Xs[c0][s0] = xv0;
        *(float4*)&Xs[c1][s0] = xv1;
        __syncthreads();
#pragma unroll
        for (int kk = 0; kk < 16; kk++) {
            float4 a  = *(const float4*)&As[kk][ty * 4];
            float4 b0 = *(const float4*)&Xs[kk][tx * 8];
            float4 b1 = *(const float4*)&Xs[kk][tx * 8 + 4];
            acc[0][0] += a.x * b0.x; acc[0][1] += a.x * b0.y; acc[0][2] += a.x * b0.z; acc[0][3] += a.x * b0.w;
            acc[0][4] += a.x * b1.x; acc[0][5] += a.x * b1.y; acc[0][6] += a.x * b1.z; acc[0][7] += a.x * b1.w;
            acc[1][0] += a.y * b0.x; acc[1][1] += a.y * b0.y; acc[1][2] += a.y * b0.z; acc[1][3] += a.y * b0.w;
            acc[1][4] += a.y * b1.x; acc[1][5] += a.y * b1.y; acc[1][6] += a.y * b1.z; acc[1][7] += a.y * b1.w;
            acc[2][0] += a.z * b0.x; acc[2][1] += a.z * b0.y; acc[2][2] += a.z * b0.z; acc[2][3] += a.z * b0.w;
            acc[2][4] += a.z * b1.x; acc[2][5] += a.z * b1.y; acc[2][6] += a.z * b1.z; acc[2][7] += a.z * b1.w;
            acc[3][0] += a.w * b0.x; acc[3][1] += a.w * b0.y; acc[3][2] += a.w * b0.z; acc[3][3] += a.w * b0.w;
            acc[3][4] += a.w * b1.x; acc[3][5] += a.w * b1.y; acc[3][6] += a.w * b1.z; acc[3][7] += a.w * b1.w;
        }
    }

#pragma unroll
    for (int r = 0; r < 4; r++) {
        int m = m0 + ty * 4 + r;
        float bias = bo[m];
        float* op = out + ((size_t)b * C_IN + m) * S_TOT + n0 + tx * 8;
        float4 v0 = { acc[r][0] + bias, acc[r][1] + bias, acc[r][2] + bias, acc[r][3] + bias };
        float4 v1 = { acc[r][4] + bias, acc[r][5] + bias, acc[r][6] + bias, acc[r][7] + bias };
        *(float4*)(op + 0) = v0;
        *(float4*)(op + 4) = v1;
    }
}

extern "C" void kernel_launch(void* const* d_in, const int* in_sizes, int n_in,
                              void* d_out, int out_size, void* d_ws, size_t ws_size,
                              hipStream_t stream) {
    const float* x  = (const float*)d_in[0];
    const float* wq = (const float*)d_in[1];
    const float* wk = (const float*)d_in[2];
    const float* wv = (const float*)d_in[3];
    const float* wo = (const float*)d_in[4];
    const float* bo = (const float*)d_in[5];
    float* out = (float*)d_out;
    float* ws  = (float*)d_ws;

    float* gG = ws + G_OFF;
    float* gT = ws + T_OFF;
    float* gM = ws + M_OFF;
    float* gW = ws + W_OFF;

    hipMemsetAsync(gG, 0, G_SZ * sizeof(float), stream);
    gram_kernel<<<dim3(3, 3, NB * KCH), 256, 0, stream>>>(x, gG);

    // T[b] = wq (512x192) * G_b (192x192)
    gemm64_kernel<<<dim3(8, 3, NB), 256, 0, stream>>>(
        wq, gG, gT, C_IN, C_IN, 0L, (long)(C_IN * C_IN), (long)(512 * C_IN));

    // sim -> softmax -> M_h, per (b, h)
    simsoftm_kernel<<<dim3(NB, NH), 256, 0, stream>>>(gT, wk, wv, gM);

    // W[b] = wo (192x512) * M_b (512x192)
    gemm64_kernel<<<dim3(3, 3, NB), 256, 0, stream>>>(
        wo, gM, gW, 512, C_IN, 0L, (long)(512 * C_IN), (long)(C_IN * C_IN));

    final_kernel<<<dim3(3, 256, NB), 256, 0, stream>>>(x, gW, bo, out);
}